// Round 7
// baseline (2993.185 us; speedup 1.0000x reference)
//
#include <hip/hip_runtime.h>
#include <hip/hip_bf16.h>
#include <stdint.h>

// SymbolicDecoder fused MLP evaluation, MI355X gfx950.  Round 7.
// Change vs round 6: restore 2 blocks/CU (the phase-overlap mechanism that
// made round 5 faster) while keeping the 256x256 big-tile reuse.  BK=32:
// LDS = (16KB A + 16KB B) x 2 buffers = 64 KB -> 2 blocks/CU, 4 waves/SIMD.
// Round 6's 128KB LDS forced 1 block/CU: its barrier-lockstep LDS-read burst
// (~2300 cyc/CU) and MFMA burst (~2480 cyc/CU) strictly serialized ->
// MfmaUtil 19%.  Two co-resident blocks overlap these phases.
// Counted-vmcnt double-buffer kept: STAGE = 4 global_load_lds per thread,
// steady-state wait vmcnt(4).  Per-XCD streams T3-first (LPT).
// d_ws layout (ushorts): [0, 6291456) weights bf16 fragment-ready;
// [6291456, 35651584) feat bf16 natural [4096][7][1024].  Total 71.3 MB.

typedef __attribute__((ext_vector_type(4))) float f32x4;
typedef __attribute__((ext_vector_type(8))) short short8;
typedef __attribute__((ext_vector_type(8))) __bf16 bf16x8;

__device__ inline unsigned short f2bf(float f) {
  union { float f; uint32_t u; } x; x.f = f;
  uint32_t u = x.u;
  return (unsigned short)((u + 0x7fffu + ((u >> 16) & 1u)) >> 16);
}

// ---------------- out init: out[b][p][c] = b2(part(p))[c] ----------------
__global__ void init_out(float* __restrict__ out,
                         const float* __restrict__ sb2,
                         const float* __restrict__ db2) {
  int i = blockIdx.x * 256 + threadIdx.x;
  if (i >= 180224) return;
  int c = i & 1;
  int p = (i >> 1) % 22;
  float v;
  if (p < 3)       v = sb2[0 + c];
  else if (p == 3) v = sb2[2 + c];
  else if (p == 4) v = sb2[4 + c];
  else if (p < 19) v = db2[c];
  else             v = sb2[6 + c];
  out[i] = v;
}

// ---------------- weight prep: f32 -> bf16, fragment-ready layout --------
// Per (kstep64, coltile) 32KB tile, 16B chunk c2 = kk*1024+nblk*64+kgrp*16+j15
//   k = kstep*64 + kk*32 + kgrp*8 + e (e=0..7) ; j = coltile*256 + nblk*16 + j15
// A BK=32 substep = contiguous half (kk) of a tile.
__global__ void prep_weights(const float* __restrict__ sw1,
                             const float* __restrict__ dw1,
                             unsigned short* __restrict__ wp) {
  int c = blockIdx.x * 256 + threadIdx.x;  // 786432 chunks total
  const float* W;
  size_t ob;
  int local;
  if (c < 524288) {
    int net = c >> 17;
    local = c & 131071;
    W = sw1 + (size_t)net * 1048576;
    ob = (size_t)net * 1048576;
  } else {
    local = c - 524288;
    W = dw1;
    ob = 4194304;
  }
  int c2 = local & 2047;
  int tile = local >> 11;
  int ct = tile & 3;
  int kstep = tile >> 2;
  int kk = c2 >> 10, nblk = (c2 >> 6) & 15, kgrp = (c2 >> 4) & 3, j15 = c2 & 15;
  int kb = kstep * 64 + kk * 32 + kgrp * 8;
  int j = ct * 256 + nblk * 16 + j15;
  short8 v;
#pragma unroll
  for (int e = 0; e < 8; e++) v[e] = (short)f2bf(W[(size_t)(kb + e) * 1024 + j]);
  *(short8*)(wp + ob + (size_t)local * 8) = v;
}

// ---------------- feat prep: f32 -> bf16, natural layout ----------------
__global__ void prep_feat(const float* __restrict__ feat,
                          unsigned short* __restrict__ fb) {
  int i = blockIdx.x * 256 + threadIdx.x;  // 3670016 chunks of 8
  const float* s = feat + (size_t)i * 8;
  f32x4 a = *(const f32x4*)s;
  f32x4 b = *(const f32x4*)(s + 4);
  short8 v;
  v[0] = (short)f2bf(a[0]); v[1] = (short)f2bf(a[1]);
  v[2] = (short)f2bf(a[2]); v[3] = (short)f2bf(a[3]);
  v[4] = (short)f2bf(b[0]); v[5] = (short)f2bf(b[1]);
  v[6] = (short)f2bf(b[2]); v[7] = (short)f2bf(b[3]);
  *(short8*)(fb + (size_t)i * 8) = v;
}

// ---------------- fused main: 256 rows x 256 cols, BK=32 ----------------
// LDS chunk layout (16B short8 index): [tile16(16)][kg(4)][r15(16)] = 1024
//   A: row = tile16*16 + r15, k = kg*8 + e    (16 KB per buffer)
//   B: col = tile16*16 + r15, same k          (16 KB per buffer)
// Fragment read for 16x16x32 MFMA: chunk = tile16*64 + lane (conflict-free).
__global__ __launch_bounds__(512, 4) void fused_main(
    const float* __restrict__ sb1, const float* __restrict__ sw2,
    const float* __restrict__ db1, const float* __restrict__ dw2,
    const unsigned short* __restrict__ wp,
    const unsigned short* __restrict__ fb, float* __restrict__ out) {
  __shared__ short8 Abuf0[1024];   // 16 KB each
  __shared__ short8 Abuf1[1024];
  __shared__ short8 Bbuf0[1024];
  __shared__ short8 Bbuf1[1024];   // 64 KB total -> 2 blocks/CU

  const int tid = threadIdx.x;
  const int lane = tid & 63;
  const int wid = tid >> 6;        // 0..7
  const int r15 = lane & 15;
  const int kg = lane >> 4;        // k-group 0..3
  const int wr = wid >> 2;         // wave row (0..1), 128 rows each
  const int wc = wid & 3;          // wave col (0..3), 64 cols each

  // Balanced per-XCD streams, T3 (64-substep) first for LPT scheduling.
  // 1408 blocks = 8 XCDs x 176: [0,112) T3 | [112,136) T0 | [136,144) T1 |
  // [144,152) T2 | [152,176) T4.  v counts ct-fastest within task.
  const int bid = blockIdx.x;
  const int x = bid & 7;
  const int j = bid >> 3;

  int task, nsteps, v;
  const unsigned short* wpt;
  const float* b1;
  const float* w2;
  if (j < 112)      { task = 3; v = x * 112 + j;        wpt = wp + 4194304; b1 = db1;        w2 = dw2;        nsteps = 64; }
  else if (j < 136) { task = 0; v = x * 24 + (j - 112); wpt = wp;           b1 = sb1;        w2 = sw2;        nsteps = 32; }
  else if (j < 144) { task = 1; v = x * 8 + (j - 136);  wpt = wp + 1048576; b1 = sb1 + 1024; w2 = sw2 + 2048; nsteps = 32; }
  else if (j < 152) { task = 2; v = x * 8 + (j - 144);  wpt = wp + 2097152; b1 = sb1 + 2048; w2 = sw2 + 4096; nsteps = 32; }
  else              { task = 4; v = x * 24 + (j - 152); wpt = wp + 3145728; b1 = sb1 + 3072; w2 = sw2 + 6144; nsteps = 32; }
  const int ct = v & 3;
  const int rbase = (v >> 2) * 256;

  // A staging pointers.  Thread (wid,lane) stages row-tiles mt=wid (batch 0)
  // and mt=wid+8 (batch 1): arow = rbase + mt*16 + r15, k-slice kg*8.
  // Two K-halves (task 3 reads a slot pair) -> 4 pointers.
  const unsigned short *a00, *a01, *a10, *a11;
#pragma unroll
  for (int rs = 0; rs < 2; rs++) {
    int arow = rbase + (rs * 8 + wid) * 16 + r15;
    int ab, as1, as2;
    if (task == 0 || task == 4) {
      ab = arow / 3; int s = arow - ab * 3; as1 = s; as2 = s;
    } else if (task == 3) {
      ab = arow / 14; int pp = arow - ab * 14;
      if (pp < 12) { as1 = pp >> 2; as2 = 3 + (pp & 3); }
      else         { as1 = 4;       as2 = (pp == 12) ? 5 : 6; }
    } else {
      ab = arow; as1 = 6; as2 = 6;
    }
    const unsigned short* q0 = fb + ((size_t)ab * 7 + as1) * 1024 + kg * 8;
    const unsigned short* q1 = fb + ((size_t)ab * 7 + as2) * 1024 + kg * 8;
    if (rs == 0) { a00 = q0; a01 = q1; } else { a10 = q0; a11 = q1; }
  }

  f32x4 acc[8][4] = {};

#define GLL(SRC, BUF, BYTEOFF)                                                \
  __builtin_amdgcn_global_load_lds(                                          \
      (const __attribute__((address_space(1))) void*)(SRC),                  \
      (__attribute__((address_space(3))) void*)((char*)(BUF) + (BYTEOFF)),   \
      16, 0, 0)

  // STAGE(t): 4 global_load_lds per thread (2 A + 2 B) -> vmcnt += 4
  // substep t: k_global = t*32; A slot-half = t<32 ? first : second;
  // B source = (kstep64 = t>>1, ct) tile, half kk = t&1.
#define STAGE(KS, AB, BB)                                                     \
  do {                                                                        \
    const int ko_ = ((KS) & 31) * 32;                                         \
    const unsigned short* r0_ = ((KS) < 32) ? a00 : a01;                      \
    const unsigned short* r1_ = ((KS) < 32) ? a10 : a11;                      \
    GLL(r0_ + ko_, AB, wid * 1024);              /* mt = wid   */             \
    GLL(r1_ + ko_, AB, 8192 + wid * 1024);       /* mt = wid+8 */             \
    const unsigned short* ws_ = wpt + (size_t)(((KS) >> 1) * 4 + ct) * 16384  \
                                    + ((KS) & 1) * 8192;                      \
    GLL(ws_ + (wid * 64 + lane) * 8, BB, wid * 1024);                         \
    GLL(ws_ + (512 + wid * 64 + lane) * 8, BB, 8192 + wid * 1024);            \
  } while (0)

  // Half-step: consume substep T from (AB,BB); re-stage T+2 into same bufs.
#define HSTEP(T, AB, BB, LAST)                                                \
  do {                                                                        \
    if (LAST) asm volatile("s_waitcnt vmcnt(0)" ::: "memory");                \
    else      asm volatile("s_waitcnt vmcnt(4)" ::: "memory");                \
    __builtin_amdgcn_s_barrier();                                             \
    short8 afr[8], bfr[4];                                                    \
    _Pragma("unroll")                                                         \
    for (int m_ = 0; m_ < 8; m_++)                                            \
      afr[m_] = (AB)[(wr * 8 + m_) * 64 + lane];                              \
    _Pragma("unroll")                                                         \
    for (int n_ = 0; n_ < 4; n_++)                                            \
      bfr[n_] = (BB)[(wc * 4 + n_) * 64 + lane];                              \
    asm volatile("s_waitcnt lgkmcnt(0)" ::: "memory");                        \
    __builtin_amdgcn_s_barrier();                                             \
    if ((T) + 2 < nsteps) STAGE((T) + 2, AB, BB);                             \
    __builtin_amdgcn_s_setprio(1);                                            \
    _Pragma("unroll")                                                         \
    for (int m_ = 0; m_ < 8; m_++)                                            \
      _Pragma("unroll")                                                       \
      for (int n_ = 0; n_ < 4; n_++)                                          \
        acc[m_][n_] = __builtin_amdgcn_mfma_f32_16x16x32_bf16(                \
            __builtin_bit_cast(bf16x8, afr[m_]),                              \
            __builtin_bit_cast(bf16x8, bfr[n_]), acc[m_][n_], 0, 0, 0);       \
    __builtin_amdgcn_s_setprio(0);                                            \
  } while (0)

  // prologue: 2 substeps in flight (8 outstanding vmem ops)
  STAGE(0, Abuf0, Bbuf0);
  STAGE(1, Abuf1, Bbuf1);

  for (int ks = 0; ks < nsteps; ks += 2) {
    HSTEP(ks,     Abuf0, Bbuf0, false);
    HSTEP(ks + 1, Abuf1, Bbuf1, (ks + 2 >= nsteps));
  }
#undef STAGE
#undef HSTEP
#undef GLL

  // ---- epilogue: h = relu(acc + b1); partial out = h . w2 ; atomicAdd ----
  float b1v[4], w20v[4], w21v[4];
#pragma unroll
  for (int n = 0; n < 4; n++) {
    int jj = ct * 256 + wc * 64 + n * 16 + r15;
    b1v[n] = b1[jj];
    w20v[n] = w2[2 * jj];
    w21v[n] = w2[2 * jj + 1];
  }
#pragma unroll
  for (int m = 0; m < 8; m++) {
#pragma unroll
    for (int r = 0; r < 4; r++) {
      float s0 = 0.f, s1 = 0.f;
#pragma unroll
      for (int n = 0; n < 4; n++) {
        float h = acc[m][n][r] + b1v[n];
        h = fmaxf(h, 0.f);
        s0 = fmaf(h, w20v[n], s0);
        s1 = fmaf(h, w21v[n], s1);
      }
#pragma unroll
      for (int off = 1; off < 16; off <<= 1) {
        s0 += __shfl_xor(s0, off, 64);
        s1 += __shfl_xor(s1, off, 64);
      }
      if (r15 == 0) {
        int rg = rbase + wr * 128 + m * 16 + (lane >> 4) * 4 + r;
        int b, p;
        if (task == 0)      { b = rg / 3;  p = rg - b * 3; }
        else if (task == 1) { b = rg;      p = 3; }
        else if (task == 2) { b = rg;      p = 4; }
        else if (task == 3) { b = rg / 14; p = 5 + (rg - b * 14); }
        else                { b = rg / 3;  p = 19 + (rg - b * 3); }
        atomicAdd(out + ((size_t)b * 44 + p * 2), s0);
        atomicAdd(out + ((size_t)b * 44 + p * 2 + 1), s1);
      }
    }
  }
}

extern "C" void kernel_launch(void* const* d_in, const int* in_sizes, int n_in,
                              void* d_out, int out_size, void* d_ws, size_t ws_size,
                              hipStream_t stream) {
  const float* feat = (const float*)d_in[0];
  const float* sw1  = (const float*)d_in[1];
  const float* sb1  = (const float*)d_in[2];
  const float* sw2  = (const float*)d_in[3];
  const float* sb2  = (const float*)d_in[4];
  const float* dw1  = (const float*)d_in[5];
  const float* db1  = (const float*)d_in[6];
  const float* dw2  = (const float*)d_in[7];
  const float* db2  = (const float*)d_in[8];
  float* out = (float*)d_out;
  unsigned short* wp = (unsigned short*)d_ws;      // 12.58 MB weights
  unsigned short* fb = wp + 6291456;               // 58.7 MB feat bf16

  init_out<<<704, 256, 0, stream>>>(out, sb2, db2);
  prep_weights<<<3072, 256, 0, stream>>>(sw1, dw1, wp);
  prep_feat<<<14336, 256, 0, stream>>>(feat, fb);
  // 1408 blocks = 8 XCD streams x 176 (112 T3 | 24 T0 | 8 T1 | 8 T2 | 24 T4)
  fused_main<<<1408, 512, 0, stream>>>(sb1, sw2, db1, dw2, wp, fb, out);
}

// Round 8
// 462.967 us; speedup vs baseline: 6.4652x; 6.4652x over previous
//
#include <hip/hip_runtime.h>
#include <hip/hip_bf16.h>
#include <stdint.h>

// SymbolicDecoder fused MLP evaluation, MI355X gfx950.  Round 8.
// Changes vs round 7 (which spilled: launch_bounds(512,4) capped regs at 128
// = acc alone -> 8.7 GB scratch writes):
//  - __launch_bounds__(512, 2): 256-reg budget, acc 8x4 + frags fit (R6
//    proved VGPR=128 + AGPRs, no spill, at this geometry).
//  - 4-deep LDS buffer rotation (BK=32, 32KB/buffer, 128KB total): prefetch
//    depth 3, steady-state s_waitcnt vmcnt(8) (counted, never 0 mid-loop),
//    ONE s_barrier per subtile (buffer being overwritten was fully read one
//    subtile ago, so the entry barrier is the only fence needed).
//  - Phase-split subtile: stage(t+3) | read A0-3,B0-3 | 16 MFMA | read A4-7
//    | 16 MFMA, setprio(1) around MFMA clusters (T5, 8-phase-gated).
// d_ws layout (ushorts): [0, 6291456) weights bf16 fragment-ready;
// [6291456, 35651584) feat bf16 natural [4096][7][1024].  Total 71.3 MB.

typedef __attribute__((ext_vector_type(4))) float f32x4;
typedef __attribute__((ext_vector_type(8))) short short8;
typedef __attribute__((ext_vector_type(8))) __bf16 bf16x8;

__device__ inline unsigned short f2bf(float f) {
  union { float f; uint32_t u; } x; x.f = f;
  uint32_t u = x.u;
  return (unsigned short)((u + 0x7fffu + ((u >> 16) & 1u)) >> 16);
}

// ---------------- out init: out[b][p][c] = b2(part(p))[c] ----------------
__global__ void init_out(float* __restrict__ out,
                         const float* __restrict__ sb2,
                         const float* __restrict__ db2) {
  int i = blockIdx.x * 256 + threadIdx.x;
  if (i >= 180224) return;
  int c = i & 1;
  int p = (i >> 1) % 22;
  float v;
  if (p < 3)       v = sb2[0 + c];
  else if (p == 3) v = sb2[2 + c];
  else if (p == 4) v = sb2[4 + c];
  else if (p < 19) v = db2[c];
  else             v = sb2[6 + c];
  out[i] = v;
}

// ---------------- weight prep: f32 -> bf16, fragment-ready layout --------
// Per (kstep64, coltile) 32KB tile, 16B chunk c2 = kk*1024+nblk*64+kgrp*16+j15
//   k = kstep*64 + kk*32 + kgrp*8 + e (e=0..7) ; j = coltile*256 + nblk*16 + j15
// A BK=32 substep = contiguous half (kk) of a tile.
__global__ void prep_weights(const float* __restrict__ sw1,
                             const float* __restrict__ dw1,
                             unsigned short* __restrict__ wp) {
  int c = blockIdx.x * 256 + threadIdx.x;  // 786432 chunks total
  const float* W;
  size_t ob;
  int local;
  if (c < 524288) {
    int net = c >> 17;
    local = c & 131071;
    W = sw1 + (size_t)net * 1048576;
    ob = (size_t)net * 1048576;
  } else {
    local = c - 524288;
    W = dw1;
    ob = 4194304;
  }
  int c2 = local & 2047;
  int tile = local >> 11;
  int ct = tile & 3;
  int kstep = tile >> 2;
  int kk = c2 >> 10, nblk = (c2 >> 6) & 15, kgrp = (c2 >> 4) & 3, j15 = c2 & 15;
  int kb = kstep * 64 + kk * 32 + kgrp * 8;
  int j = ct * 256 + nblk * 16 + j15;
  short8 v;
#pragma unroll
  for (int e = 0; e < 8; e++) v[e] = (short)f2bf(W[(size_t)(kb + e) * 1024 + j]);
  *(short8*)(wp + ob + (size_t)local * 8) = v;
}

// ---------------- feat prep: f32 -> bf16, natural layout ----------------
__global__ void prep_feat(const float* __restrict__ feat,
                          unsigned short* __restrict__ fb) {
  int i = blockIdx.x * 256 + threadIdx.x;  // 3670016 chunks of 8
  const float* s = feat + (size_t)i * 8;
  f32x4 a = *(const f32x4*)s;
  f32x4 b = *(const f32x4*)(s + 4);
  short8 v;
  v[0] = (short)f2bf(a[0]); v[1] = (short)f2bf(a[1]);
  v[2] = (short)f2bf(a[2]); v[3] = (short)f2bf(a[3]);
  v[4] = (short)f2bf(b[0]); v[5] = (short)f2bf(b[1]);
  v[6] = (short)f2bf(b[2]); v[7] = (short)f2bf(b[3]);
  *(short8*)(fb + (size_t)i * 8) = v;
}

// ---------------- fused main: 256 rows x 256 cols, BK=32, 4-deep ---------
// LDS chunk layout (16B short8 index): [tile16(16)][kg(4)][r15(16)] = 1024
//   A: row = tile16*16 + r15, k = kg*8 + e    (16 KB per buffer)
//   B: col = tile16*16 + r15, same k          (16 KB per buffer)
// Fragment read: chunk = tile16*64 + lane -> lane-consecutive 16B, no bank
// conflicts (measured 0 across rounds).
__global__ __launch_bounds__(512, 2) void fused_main(
    const float* __restrict__ sb1, const float* __restrict__ sw2,
    const float* __restrict__ db1, const float* __restrict__ dw2,
    const unsigned short* __restrict__ wp,
    const unsigned short* __restrict__ fb, float* __restrict__ out) {
  __shared__ short8 Ab0[1024];  // 16 KB each; 8 arrays = 128 KB total
  __shared__ short8 Ab1[1024];
  __shared__ short8 Ab2[1024];
  __shared__ short8 Ab3[1024];
  __shared__ short8 Bb0[1024];
  __shared__ short8 Bb1[1024];
  __shared__ short8 Bb2[1024];
  __shared__ short8 Bb3[1024];

  const int tid = threadIdx.x;
  const int lane = tid & 63;
  const int wid = tid >> 6;        // 0..7
  const int r15 = lane & 15;
  const int kg = lane >> 4;        // k-group 0..3
  const int wr = wid >> 2;         // wave row (0..1), 128 rows each
  const int wc = wid & 3;          // wave col (0..3), 64 cols each

  // Balanced per-XCD streams, T3 (64-substep) first for LPT scheduling.
  // 1408 blocks = 8 XCDs x 176: [0,112) T3 | [112,136) T0 | [136,144) T1 |
  // [144,152) T2 | [152,176) T4.  v counts ct-fastest within task.
  const int bid = blockIdx.x;
  const int x = bid & 7;
  const int j = bid >> 3;

  int task, nsteps, v;
  const unsigned short* wpt;
  const float* b1;
  const float* w2;
  if (j < 112)      { task = 3; v = x * 112 + j;        wpt = wp + 4194304; b1 = db1;        w2 = dw2;        nsteps = 64; }
  else if (j < 136) { task = 0; v = x * 24 + (j - 112); wpt = wp;           b1 = sb1;        w2 = sw2;        nsteps = 32; }
  else if (j < 144) { task = 1; v = x * 8 + (j - 136);  wpt = wp + 1048576; b1 = sb1 + 1024; w2 = sw2 + 2048; nsteps = 32; }
  else if (j < 152) { task = 2; v = x * 8 + (j - 144);  wpt = wp + 2097152; b1 = sb1 + 2048; w2 = sw2 + 4096; nsteps = 32; }
  else              { task = 4; v = x * 24 + (j - 152); wpt = wp + 3145728; b1 = sb1 + 3072; w2 = sw2 + 6144; nsteps = 32; }
  const int ct = v & 3;
  const int rbase = (v >> 2) * 256;

  // A staging pointers.  Thread (wid,lane) stages row-tiles mt=wid and
  // mt=wid+8: arow = rbase + mt*16 + r15, k-slice kg*8.  Two K-halves
  // (task 3 reads a slot pair) -> 4 pointers.
  const unsigned short *a00, *a01, *a10, *a11;
#pragma unroll
  for (int rs = 0; rs < 2; rs++) {
    int arow = rbase + (rs * 8 + wid) * 16 + r15;
    int ab, as1, as2;
    if (task == 0 || task == 4) {
      ab = arow / 3; int s = arow - ab * 3; as1 = s; as2 = s;
    } else if (task == 3) {
      ab = arow / 14; int pp = arow - ab * 14;
      if (pp < 12) { as1 = pp >> 2; as2 = 3 + (pp & 3); }
      else         { as1 = 4;       as2 = (pp == 12) ? 5 : 6; }
    } else {
      ab = arow; as1 = 6; as2 = 6;
    }
    const unsigned short* q0 = fb + ((size_t)ab * 7 + as1) * 1024 + kg * 8;
    const unsigned short* q1 = fb + ((size_t)ab * 7 + as2) * 1024 + kg * 8;
    if (rs == 0) { a00 = q0; a01 = q1; } else { a10 = q0; a11 = q1; }
  }

  f32x4 acc[8][4] = {};

#define GLL(SRC, BUF, BYTEOFF)                                                \
  __builtin_amdgcn_global_load_lds(                                          \
      (const __attribute__((address_space(1))) void*)(SRC),                  \
      (__attribute__((address_space(3))) void*)((char*)(BUF) + (BYTEOFF)),   \
      16, 0, 0)

  // STAGE(t): 4 global_load_lds per thread (2 A + 2 B) -> vmcnt += 4
#define STAGE(KS, AB, BB)                                                     \
  do {                                                                        \
    const int ko_ = ((KS) & 31) * 32;                                         \
    const unsigned short* r0_ = ((KS) < 32) ? a00 : a01;                      \
    const unsigned short* r1_ = ((KS) < 32) ? a10 : a11;                      \
    GLL(r0_ + ko_, AB, wid * 1024);              /* mt = wid   */             \
    GLL(r1_ + ko_, AB, 8192 + wid * 1024);       /* mt = wid+8 */             \
    const unsigned short* ws_ = wpt + (size_t)(((KS) >> 1) * 4 + ct) * 16384  \
                                    + ((KS) & 1) * 8192;                      \
    GLL(ws_ + (wid * 64 + lane) * 8, BB, wid * 1024);                         \
    GLL(ws_ + (512 + wid * 64 + lane) * 8, BB, 8192 + wid * 1024);            \
  } while (0)

  // SUB(t): one subtile.  Entry: counted vmcnt (8 steady / 4 / 0 tail) +
  // single barrier.  Then prefetch t+3 into the buffer read at t-1, read
  // fragments, two 16-MFMA clusters under setprio(1).
#define SUB(T, AB, BB, NAB, NBB)                                              \
  do {                                                                        \
    if ((T) + 2 < nsteps)                                                     \
      asm volatile("s_waitcnt vmcnt(8)" ::: "memory");                        \
    else if ((T) + 1 < nsteps)                                                \
      asm volatile("s_waitcnt vmcnt(4)" ::: "memory");                        \
    else                                                                      \
      asm volatile("s_waitcnt vmcnt(0)" ::: "memory");                        \
    __builtin_amdgcn_s_barrier();                                             \
    if ((T) + 3 < nsteps) STAGE((T) + 3, NAB, NBB);                           \
    short8 afr0[4], afr1[4], bfr[4];                                          \
    _Pragma("unroll")                                                         \
    for (int m_ = 0; m_ < 4; m_++)                                            \
      afr0[m_] = (AB)[(wr * 8 + m_) * 64 + lane];                             \
    _Pragma("unroll")                                                         \
    for (int n_ = 0; n_ < 4; n_++)                                            \
      bfr[n_] = (BB)[(wc * 4 + n_) * 64 + lane];                              \
    __builtin_amdgcn_s_setprio(1);                                            \
    _Pragma("unroll")                                                         \
    for (int m_ = 0; m_ < 4; m_++)                                            \
      _Pragma("unroll")                                                       \
      for (int n_ = 0; n_ < 4; n_++)                                          \
        acc[m_][n_] = __builtin_amdgcn_mfma_f32_16x16x32_bf16(                \
            __builtin_bit_cast(bf16x8, afr0[m_]),                             \
            __builtin_bit_cast(bf16x8, bfr[n_]), acc[m_][n_], 0, 0, 0);       \
    __builtin_amdgcn_s_setprio(0);                                            \
    _Pragma("unroll")                                                         \
    for (int m_ = 0; m_ < 4; m_++)                                            \
      afr1[m_] = (AB)[(wr * 8 + 4 + m_) * 64 + lane];                         \
    __builtin_amdgcn_s_setprio(1);                                            \
    _Pragma("unroll")                                                         \
    for (int m_ = 0; m_ < 4; m_++)                                            \
      _Pragma("unroll")                                                       \
      for (int n_ = 0; n_ < 4; n_++)                                          \
        acc[4 + m_][n_] = __builtin_amdgcn_mfma_f32_16x16x32_bf16(            \
            __builtin_bit_cast(bf16x8, afr1[m_]),                             \
            __builtin_bit_cast(bf16x8, bfr[n_]), acc[4 + m_][n_], 0, 0, 0);   \
    __builtin_amdgcn_s_setprio(0);                                            \
  } while (0)

  // prologue: 3 subtiles in flight (12 outstanding vmem ops)
  STAGE(0, Ab0, Bb0);
  STAGE(1, Ab1, Bb1);
  STAGE(2, Ab2, Bb2);

  for (int ts = 0; ts < nsteps; ts += 4) {
    SUB(ts + 0, Ab0, Bb0, Ab3, Bb3);
    SUB(ts + 1, Ab1, Bb1, Ab0, Bb0);
    SUB(ts + 2, Ab2, Bb2, Ab1, Bb1);
    SUB(ts + 3, Ab3, Bb3, Ab2, Bb2);
  }
#undef SUB
#undef STAGE
#undef GLL

  // ---- epilogue: h = relu(acc + b1); partial out = h . w2 ; atomicAdd ----
  float b1v[4], w20v[4], w21v[4];
#pragma unroll
  for (int n = 0; n < 4; n++) {
    int jj = ct * 256 + wc * 64 + n * 16 + r15;
    b1v[n] = b1[jj];
    w20v[n] = w2[2 * jj];
    w21v[n] = w2[2 * jj + 1];
  }
#pragma unroll
  for (int m = 0; m < 8; m++) {
#pragma unroll
    for (int r = 0; r < 4; r++) {
      float s0 = 0.f, s1 = 0.f;
#pragma unroll
      for (int n = 0; n < 4; n++) {
        float h = acc[m][n][r] + b1v[n];
        h = fmaxf(h, 0.f);
        s0 = fmaf(h, w20v[n], s0);
        s1 = fmaf(h, w21v[n], s1);
      }
#pragma unroll
      for (int off = 1; off < 16; off <<= 1) {
        s0 += __shfl_xor(s0, off, 64);
        s1 += __shfl_xor(s1, off, 64);
      }
      if (r15 == 0) {
        int rg = rbase + wr * 128 + m * 16 + (lane >> 4) * 4 + r;
        int b, p;
        if (task == 0)      { b = rg / 3;  p = rg - b * 3; }
        else if (task == 1) { b = rg;      p = 3; }
        else if (task == 2) { b = rg;      p = 4; }
        else if (task == 3) { b = rg / 14; p = 5 + (rg - b * 14); }
        else                { b = rg / 3;  p = 19 + (rg - b * 3); }
        atomicAdd(out + ((size_t)b * 44 + p * 2), s0);
        atomicAdd(out + ((size_t)b * 44 + p * 2 + 1), s1);
      }
    }
  }
}

extern "C" void kernel_launch(void* const* d_in, const int* in_sizes, int n_in,
                              void* d_out, int out_size, void* d_ws, size_t ws_size,
                              hipStream_t stream) {
  const float* feat = (const float*)d_in[0];
  const float* sw1  = (const float*)d_in[1];
  const float* sb1  = (const float*)d_in[2];
  const float* sw2  = (const float*)d_in[3];
  const float* sb2  = (const float*)d_in[4];
  const float* dw1  = (const float*)d_in[5];
  const float* db1  = (const float*)d_in[6];
  const float* dw2  = (const float*)d_in[7];
  const float* db2  = (const float*)d_in[8];
  float* out = (float*)d_out;
  unsigned short* wp = (unsigned short*)d_ws;      // 12.58 MB weights
  unsigned short* fb = wp + 6291456;               // 58.7 MB feat bf16

  init_out<<<704, 256, 0, stream>>>(out, sb2, db2);
  prep_weights<<<3072, 256, 0, stream>>>(sw1, dw1, wp);
  prep_feat<<<14336, 256, 0, stream>>>(feat, fb);
  // 1408 blocks = 8 XCD streams x 176 (112 T3 | 24 T0 | 8 T1 | 8 T2 | 24 T4)
  fused_main<<<1408, 512, 0, stream>>>(sb1, sw2, db1, dw2, wp, fb, out);
}